// Round 12
// baseline (277.858 us; speedup 1.0000x reference)
//
#include <hip/hip_runtime.h>
#include <hip/hip_bf16.h>

#define NN  50000
#define NE  1600000
#define DIM 64
#define NBK 391          // 128-node buckets

// ---- ws layout (int32 offsets) -------------------------------------------
#define OFF_FLAGS  0            // 8 ints
#define OFF_BCURP  8            // 391*16 padded cursors (64B/bucket, atomics)
#define OFF_EIDX   6272         // padded records: [bucket][PADCAP]

#define CHUNK 8192   // edges per k_parta block
#define QCAP  2304   // per-quarter record capacity in k_node

typedef __bf16 bf16x8 __attribute__((ext_vector_type(8)));
typedef __bf16 bf16x4 __attribute__((ext_vector_type(4)));
typedef float  f32x4  __attribute__((ext_vector_type(4)));

__device__ __forceinline__ float loadF(const void* p, int i, int bf) {
  if (bf) return __bfloat162float(((const __hip_bfloat16*)p)[i]);
  return ((const float*)p)[i];
}

__device__ __forceinline__ float4 loadF4(const void* p, int i4, int bf) {
  if (bf) {
    ushort4 u = ((const ushort4*)p)[i4];
    float4 f;
    union { unsigned int ui; float fl; } c;
    c.ui = (unsigned int)u.x << 16; f.x = c.fl;
    c.ui = (unsigned int)u.y << 16; f.y = c.fl;
    c.ui = (unsigned int)u.z << 16; f.z = c.fl;
    c.ui = (unsigned int)u.w << 16; f.w = c.fl;
    return f;
  }
  return ((const float4*)p)[i4];
}

__device__ __forceinline__ void accumF(float4 a, float4 r,
                                       float4& s4, float4& q4) {
  float tx = a.x * r.x, ty = a.y * r.y, tz = a.z * r.z, tw = a.w * r.w;
  s4.x += tx; q4.x = fmaf(tx, tx, q4.x);
  s4.y += ty; q4.y = fmaf(ty, ty, q4.y);
  s4.z += tz; q4.z = fmaf(tz, tz, q4.z);
  s4.w += tw; q4.w = fmaf(tw, tw, q4.w);
}

// Per-array dtype detection + zero padded bucket cursors.
__global__ void k_detect(const void* input, const void* boundary,
                         const void* relw, const void* W, const void* ew,
                         int* flags, int* bcurp) {
  __shared__ int cnt;
  int t = threadIdx.x;  // 64 threads
  const void* arrs[4] = {input, boundary, relw, W};
  for (int a = 0; a < 4; ++a) {
    if (t == 0) cnt = 0;
    __syncthreads();
    const unsigned short* u = (const unsigned short*)arrs[a];
    unsigned ex = (u[2 * t] >> 7) & 0xFF;
    if (ex >= 100 && ex <= 140) atomicAdd(&cnt, 1);
    __syncthreads();
    if (t == 0) flags[a] = (cnt >= 32) ? 1 : 0;
    __syncthreads();
  }
  if (t == 0) {
    flags[4] = (((const unsigned short*)ew)[0] == 0x3F80) ? 1 : 0;
    flags[5] = 1;
  }
  for (int i = t; i < NBK * 16; i += 64) bcurp[i] = 0;
}

// Exact all-ones check of edge weights.
__global__ __launch_bounds__(256) void k_ew(const void* __restrict__ ew,
                                            int* __restrict__ flags) {
  int bfE = flags[4];
  int c0 = blockIdx.x * 8192;
  int bad = 0;
  for (int i = threadIdx.x; i < 8192; i += 256) {
    int e = c0 + i;
    if (e < NE && loadF(ew, e, bfE) != 1.0f) bad = 1;
  }
  if (bad) flags[5] = 0;
}

// Partition edges into PADDED per-bucket regions via LDS staging (R11).
__global__ __launch_bounds__(1024) void k_parta(
    const int* __restrict__ el, int* __restrict__ bcurp,
    int* __restrict__ eidx, const int* __restrict__ flags,
    int gb0, int gb1, int padcap) {
  __shared__ int stage[CHUNK];              // 32 KB
  __shared__ unsigned short sbk[CHUNK];     // 16 KB
  __shared__ int lh[NBK], lbase[NBK], lh2[NBK], gbs[NBK];
  __shared__ int sc[256];
  __shared__ int total;
  int t = threadIdx.x;
  int nb = gb1 - gb0;
  int c0 = blockIdx.x * CHUNK;
  int ones = flags[5];
  for (int i = t; i < nb; i += 1024) { lh[i] = 0; lh2[i] = 0; }
  __syncthreads();

  int rec[8], bb[8];
  #pragma unroll
  for (int j = 0; j < 8; ++j) {
    int e = c0 + j * 1024 + t;
    bb[j] = -1; rec[j] = 0;
    if (e < NE) {
      int n0 = el[e * 3], n1 = el[e * 3 + 1], n2 = el[e * 3 + 2];
      int b = (n1 >> 7) - gb0;
      if (b >= 0 && b < nb) {
        bb[j] = b;
        rec[j] = ones ? (n0 | (n2 << 16) | ((n1 & 127) << 25))
                      : (e | ((n1 & 127) << 25));
        atomicAdd(&lh[b], 1);
      }
    }
  }
  __syncthreads();

  int a0 = 0, a1 = 0;
  if (t < 256) {
    a0 = (2 * t < nb) ? lh[2 * t] : 0;
    a1 = (2 * t + 1 < nb) ? lh[2 * t + 1] : 0;
    sc[t] = a0 + a1;
  }
  __syncthreads();
  for (int off = 1; off < 256; off <<= 1) {
    int v = 0;
    if (t < 256 && t >= off) v = sc[t - off];
    __syncthreads();
    if (t < 256) sc[t] += v;
    __syncthreads();
  }
  if (t < 256) {
    int excl = sc[t] - (a0 + a1);
    if (2 * t < nb) {
      lbase[2 * t] = excl;
      if (a0 > 0) gbs[2 * t] = atomicAdd(&bcurp[(gb0 + 2 * t) * 16], a0);
    }
    if (2 * t + 1 < nb) {
      lbase[2 * t + 1] = excl + a0;
      if (a1 > 0)
        gbs[2 * t + 1] = atomicAdd(&bcurp[(gb0 + 2 * t + 1) * 16], a1);
    }
    if (t == 255) total = sc[255];
  }
  __syncthreads();

  #pragma unroll
  for (int j = 0; j < 8; ++j) {
    if (bb[j] >= 0) {
      int r = atomicAdd(&lh2[bb[j]], 1);
      int slot = lbase[bb[j]] + r;
      stage[slot] = rec[j];
      sbk[slot] = (unsigned short)bb[j];
    }
  }
  __syncthreads();

  int tot = total;
  for (int i = t; i < tot; i += 1024) {
    int b = sbk[i];
    int slot = gbs[b] + (i - lbase[b]);
    if (slot < padcap) eidx[(long)b * padcap + slot] = stage[i];
  }
}

// R11 k_node (verified 95.8us, 212.5us total): quarter-split fused sort+node.
__global__ __launch_bounds__(256, 8) void k_node(
    const void* __restrict__ input, const void* __restrict__ boundary,
    const int* __restrict__ el, const void* __restrict__ ew,
    const void* __restrict__ relw, const void* __restrict__ W,
    const void* __restrict__ bv, const int* __restrict__ bcurp,
    const int* __restrict__ eidx, const int* __restrict__ flags,
    void* __restrict__ out, int gb0, int hi, int padcap) {
  __shared__ int ld[QCAP];
  __shared__ int ld2[QCAP];
  __shared__ int lstart[32], lend[32], lcnt[32];
  __shared__ int nf, ovf;
  __bf16 (*updb)[72] = reinterpret_cast<__bf16(*)[72]>(ld);

  int bfI = flags[0], bfB = flags[1], bfR = flags[2], bfW = flags[3],
      bfE = flags[4], ones = flags[5];
  int t = threadIdx.x;
  int wv = t >> 6, ln = t & 63;
  int g = ln >> 4;
  int k = ln & 15;
  int q = ln >> 4;
  int Bl = blockIdx.x >> 2;
  int B  = gb0 + Bl;
  int quarter = blockIdx.x & 3;
  int n0 = B * 128 + quarter * 32;
  int cnt = bcurp[B * 16];
  const int* myeidx = eidx + (long)Bl * padcap;

  if (t == 0) { nf = 0; ovf = (cnt > padcap) ? 1 : 0; }
  if (t < 32) lcnt[t] = 0;
  __syncthreads();

  int cl = cnt < padcap ? cnt : padcap;
  for (int i = t; i < cl; i += 256) {
    int rc = myeidx[i];
    if ((((unsigned)rc) >> 30) == (unsigned)quarter) {
      int p = atomicAdd(&nf, 1);
      if (p < QCAP) ld[p] = rc; else ovf = 1;
    }
  }
  __syncthreads();
  int fast = !ovf;
  int nq = nf < QCAP ? nf : QCAP;

  if (fast) {
    for (int i = t; i < nq; i += 256)
      atomicAdd(&lcnt[(((unsigned)ld[i]) >> 25) & 31], 1);
  }
  __syncthreads();
  if (t < 32) lend[t] = lcnt[t];
  __syncthreads();
  for (int off = 1; off < 32; off <<= 1) {
    int v = 0;
    if (t < 32 && t >= off) v = lend[t - off];
    __syncthreads();
    if (t < 32) lend[t] += v;
    __syncthreads();
  }
  if (t < 32) { lstart[t] = lend[t] - lcnt[t]; lcnt[t] = 0; }
  __syncthreads();
  if (fast) {
    for (int i = t; i < nq; i += 256) {
      int rc = ld[i];
      int l = (((unsigned)rc) >> 25) & 31;
      int r = atomicAdd(&lcnt[l], 1);
      ld2[lstart[l] + r] = rc;
    }
  }
  __syncthreads();

  const float4* inp4 = (const float4*)input;
  const float4* rw4  = (const float4*)relw;
  int hot = (!bfI && !bfR && ones) ? 1 : 0;

  for (int rr = 0; rr < 8; ++rr) {
    int row = wv * 8 + rr;
    int n = n0 + row;
    if (n >= hi) {
      if (g == 0) *(bf16x4*)&updb[row][4 * k] =
          bf16x4{(__bf16)0.f, (__bf16)0.f, (__bf16)0.f, (__bf16)0.f};
      continue;
    }
    float4 s4 = {0.f,0.f,0.f,0.f}, q4 = {0.f,0.f,0.f,0.f};
    float degf = 0.f;
    if (fast) {
      int start = lstart[row], end = lend[row];
      degf = (float)(end - start);
      if (hot) {
        for (int base = start; base < end; base += 64) {
          int mm = end - base; if (mm > 64) mm = 64;
          int rec = 0;
          if (ln < mm) rec = ld2[base + ln];
          int jq = mm >> 2;
          int jmax = (mm + 3) >> 2;
          int j = 0;
          for (; j + 4 <= jq; j += 4) {
            int pk0 = __shfl(rec, j * 4 + g);
            int pk1 = __shfl(rec, j * 4 + 4 + g);
            int pk2 = __shfl(rec, j * 4 + 8 + g);
            int pk3 = __shfl(rec, j * 4 + 12 + g);
            float4 a0 = inp4[(pk0 & 0xFFFF) * 16 + k];
            float4 r0 = rw4[((pk0 >> 16) & 0x1FF) * 16 + k];
            float4 a1 = inp4[(pk1 & 0xFFFF) * 16 + k];
            float4 r1 = rw4[((pk1 >> 16) & 0x1FF) * 16 + k];
            float4 a2 = inp4[(pk2 & 0xFFFF) * 16 + k];
            float4 r2 = rw4[((pk2 >> 16) & 0x1FF) * 16 + k];
            float4 a3 = inp4[(pk3 & 0xFFFF) * 16 + k];
            float4 r3 = rw4[((pk3 >> 16) & 0x1FF) * 16 + k];
            accumF(a0, r0, s4, q4);
            accumF(a1, r1, s4, q4);
            accumF(a2, r2, s4, q4);
            accumF(a3, r3, s4, q4);
          }
          for (; j < jq; ++j) {
            int pk = __shfl(rec, j * 4 + g);
            float4 a = inp4[(pk & 0xFFFF) * 16 + k];
            float4 r = rw4[((pk >> 16) & 0x1FF) * 16 + k];
            accumF(a, r, s4, q4);
          }
          for (; j < jmax; ++j) {
            int slot = j * 4 + g;
            int pk = __shfl(rec, slot & 63);
            float wsel = (slot < mm) ? 1.0f : 0.0f;
            float4 a = inp4[(pk & 0xFFFF) * 16 + k];
            float4 r = rw4[((pk >> 16) & 0x1FF) * 16 + k];
            float tx = a.x*r.x, ty = a.y*r.y, tz = a.z*r.z, tw = a.w*r.w;
            s4.x = fmaf(wsel, tx, s4.x); q4.x = fmaf(wsel*tx, tx, q4.x);
            s4.y = fmaf(wsel, ty, s4.y); q4.y = fmaf(wsel*ty, ty, q4.y);
            s4.z = fmaf(wsel, tz, s4.z); q4.z = fmaf(wsel*tz, tz, q4.z);
            s4.w = fmaf(wsel, tw, s4.w); q4.w = fmaf(wsel*tw, tw, q4.w);
          }
        }
      } else {
        for (int base = start; base < end; base += 64) {
          int mm = end - base; if (mm > 64) mm = 64;
          int rec = 0; float wrec = 0.0f;
          if (ln < mm) {
            rec = ld2[base + ln] & 0x1FFFFFF;
            if (!ones) wrec = loadF(ew, rec, bfE);
          }
          int jmax = (mm + 3) >> 2;
          for (int j = 0; j < jmax; ++j) {
            int slot = j * 4 + g;
            int rj = __shfl(rec, slot);
            int nin, rl; float wj;
            if (ones) { nin = rj & 0xFFFF; rl = (rj >> 16) & 0x1FF; wj = 1.0f; }
            else      { nin = el[rj * 3]; rl = el[rj * 3 + 2];
                        wj = __shfl(wrec, slot); }
            float wsel = (slot < mm) ? wj : 0.0f;
            float4 a = loadF4(input, nin * 16 + k, bfI);
            float4 r = loadF4(relw, rl * 16 + k, bfR);
            float tx = a.x*r.x, ty = a.y*r.y, tz = a.z*r.z, tw = a.w*r.w;
            s4.x = fmaf(wsel, tx, s4.x); q4.x = fmaf(wsel*tx, tx, q4.x);
            s4.y = fmaf(wsel, ty, s4.y); q4.y = fmaf(wsel*ty, ty, q4.y);
            s4.z = fmaf(wsel, tz, s4.z); q4.z = fmaf(wsel*tz, tz, q4.z);
            s4.w = fmaf(wsel, tw, s4.w); q4.w = fmaf(wsel*tw, tw, q4.w);
          }
        }
      }
    } else {
      float degc = 0.f;
      for (int e0 = g; e0 < NE; e0 += 4) {
        int nout = el[e0 * 3 + 1];
        if (nout != n) continue;
        degc += 1.0f;
        int nin = el[e0 * 3], rl = el[e0 * 3 + 2];
        float wj = ones ? 1.0f : loadF(ew, e0, bfE);
        float4 a = loadF4(input, nin * 16 + k, bfI);
        float4 r = loadF4(relw, rl * 16 + k, bfR);
        float tx = wj*a.x*r.x, ty = wj*a.y*r.y, tz = wj*a.z*r.z,
              tw = wj*a.w*r.w;
        s4.x += tx; q4.x = fmaf(tx, tx, q4.x);
        s4.y += ty; q4.y = fmaf(ty, ty, q4.y);
        s4.z += tz; q4.z = fmaf(tz, tz, q4.z);
        s4.w += tw; q4.w = fmaf(tw, tw, q4.w);
      }
      degc += __shfl_xor(degc, 16); degc += __shfl_xor(degc, 32);
      degf = degc;
    }
    s4.x += __shfl_xor(s4.x, 16); s4.x += __shfl_xor(s4.x, 32);
    s4.y += __shfl_xor(s4.y, 16); s4.y += __shfl_xor(s4.y, 32);
    s4.z += __shfl_xor(s4.z, 16); s4.z += __shfl_xor(s4.z, 32);
    s4.w += __shfl_xor(s4.w, 16); s4.w += __shfl_xor(s4.w, 32);
    q4.x += __shfl_xor(q4.x, 16); q4.x += __shfl_xor(q4.x, 32);
    q4.y += __shfl_xor(q4.y, 16); q4.y += __shfl_xor(q4.y, 32);
    q4.z += __shfl_xor(q4.z, 16); q4.z += __shfl_xor(q4.z, 32);
    q4.w += __shfl_xor(q4.w, 16); q4.w += __shfl_xor(q4.w, 32);
    if (g == 0) {
      float4 b4 = loadF4(boundary, n * 16 + k, bfB);
      float dg = degf + 1.0f;
      float sv, qv;
      bf16x4 u;
      sv = (s4.x + b4.x) / dg; qv = (q4.x + b4.x * b4.x) / dg;
      u[0] = (__bf16)sqrtf(fmaxf(qv - sv * sv, 1e-6f));
      sv = (s4.y + b4.y) / dg; qv = (q4.y + b4.y * b4.y) / dg;
      u[1] = (__bf16)sqrtf(fmaxf(qv - sv * sv, 1e-6f));
      sv = (s4.z + b4.z) / dg; qv = (q4.z + b4.z * b4.z) / dg;
      u[2] = (__bf16)sqrtf(fmaxf(qv - sv * sv, 1e-6f));
      sv = (s4.w + b4.w) / dg; qv = (q4.w + b4.w * b4.w) / dg;
      u[3] = (__bf16)sqrtf(fmaxf(qv - sv * sv, 1e-6f));
      *(bf16x4*)&updb[row][4 * k] = u;
    }
  }
  __syncthreads();

  int tt = wv >> 1, chh = wv & 1;
  bf16x8 af0 = *(const bf16x8*)&updb[tt * 16 + (ln & 15)][q * 8];
  bf16x8 af1 = *(const bf16x8*)&updb[tt * 16 + (ln & 15)][32 + q * 8];
  #pragma unroll
  for (int hh = 0; hh < 2; ++hh) {
    int cc = chh * 32 + hh * 16 + (ln & 15);
    bf16x8 bfr0, bfr1;
    #pragma unroll
    for (int j = 0; j < 8; ++j) {
      bfr0[j] = (__bf16)loadF(W, cc * 64 + q * 8 + j, bfW);
      bfr1[j] = (__bf16)loadF(W, cc * 64 + 32 + q * 8 + j, bfW);
    }
    float bias = loadF(bv, cc, bfW);
    f32x4 accv = {0.f, 0.f, 0.f, 0.f};
    accv = __builtin_amdgcn_mfma_f32_16x16x32_bf16(af0, bfr0, accv, 0, 0, 0);
    accv = __builtin_amdgcn_mfma_f32_16x16x32_bf16(af1, bfr1, accv, 0, 0, 0);
    #pragma unroll
    for (int i = 0; i < 4; ++i) {
      int nn = n0 + tt * 16 + q * 4 + i;
      if (nn < hi) {
        float v = accv[i] + bias;
        if (bfI) ((__hip_bfloat16*)out)[nn * 64 + cc] = __float2bfloat16(v);
        else     ((float*)out)[nn * 64 + cc] = v;
      }
    }
  }
}

// ABLATION PROBE (R12): byte-for-byte clone of k_node's fast+hot phase with
// gather rows masked &63 (both tables L1-resident, 16+16 KB). Same records,
// same sort, same shfl/addr/accum instruction stream. Output kept live via
// wave-XOR + one atomicOr/wave into a bcurp pad slot (no DCE, no contention,
// real out untouched). Duration lands in rocprof top-5 -> decides whether
// k_node's 96us is memory-system (probe ~25us) or structure (probe ~90us).
__global__ __launch_bounds__(256, 8) void k_probe(
    const void* __restrict__ input, const void* __restrict__ boundary,
    const void* __restrict__ relw, const void* __restrict__ W,
    const void* __restrict__ bv, int* __restrict__ bcurp,
    const int* __restrict__ eidx, const int* __restrict__ flags,
    int gb0, int hi, int padcap) {
  __shared__ int ld[QCAP];
  __shared__ int ld2[QCAP];
  __shared__ int lstart[32], lend[32], lcnt[32];
  __shared__ int nf, ovf;
  __bf16 (*updb)[72] = reinterpret_cast<__bf16(*)[72]>(ld);

  int bfI = flags[0], bfB = flags[1], bfR = flags[2], bfW = flags[3],
      ones = flags[5];
  int t = threadIdx.x;
  int wv = t >> 6, ln = t & 63;
  int g = ln >> 4;
  int k = ln & 15;
  int q = ln >> 4;
  int Bl = blockIdx.x >> 2;
  int B  = gb0 + Bl;
  int quarter = blockIdx.x & 3;
  int n0 = B * 128 + quarter * 32;
  int cnt = bcurp[B * 16];
  const int* myeidx = eidx + (long)Bl * padcap;

  if (t == 0) { nf = 0; ovf = (cnt > padcap) ? 1 : 0; }
  if (t < 32) lcnt[t] = 0;
  __syncthreads();

  int cl = cnt < padcap ? cnt : padcap;
  for (int i = t; i < cl; i += 256) {
    int rc = myeidx[i];
    if ((((unsigned)rc) >> 30) == (unsigned)quarter) {
      int p = atomicAdd(&nf, 1);
      if (p < QCAP) ld[p] = rc; else ovf = 1;
    }
  }
  __syncthreads();
  int fast = !ovf;
  int nq = nf < QCAP ? nf : QCAP;

  if (fast) {
    for (int i = t; i < nq; i += 256)
      atomicAdd(&lcnt[(((unsigned)ld[i]) >> 25) & 31], 1);
  }
  __syncthreads();
  if (t < 32) lend[t] = lcnt[t];
  __syncthreads();
  for (int off = 1; off < 32; off <<= 1) {
    int v = 0;
    if (t < 32 && t >= off) v = lend[t - off];
    __syncthreads();
    if (t < 32) lend[t] += v;
    __syncthreads();
  }
  if (t < 32) { lstart[t] = lend[t] - lcnt[t]; lcnt[t] = 0; }
  __syncthreads();
  if (fast) {
    for (int i = t; i < nq; i += 256) {
      int rc = ld[i];
      int l = (((unsigned)rc) >> 25) & 31;
      int r = atomicAdd(&lcnt[l], 1);
      ld2[lstart[l] + r] = rc;
    }
  }
  __syncthreads();

  const float4* inp4 = (const float4*)input;
  const float4* rw4  = (const float4*)relw;
  int hot = (!bfI && !bfR && ones) ? 1 : 0;

  for (int rr = 0; rr < 8; ++rr) {
    int row = wv * 8 + rr;
    int n = n0 + row;
    if (n >= hi) {
      if (g == 0) *(bf16x4*)&updb[row][4 * k] =
          bf16x4{(__bf16)0.f, (__bf16)0.f, (__bf16)0.f, (__bf16)0.f};
      continue;
    }
    float4 s4 = {0.f,0.f,0.f,0.f}, q4 = {0.f,0.f,0.f,0.f};
    float degf = 0.f;
    if (fast && hot) {
      int start = lstart[row], end = lend[row];
      degf = (float)(end - start);
      for (int base = start; base < end; base += 64) {
        int mm = end - base; if (mm > 64) mm = 64;
        int rec = 0;
        if (ln < mm) rec = ld2[base + ln];
        int jq = mm >> 2;
        int jmax = (mm + 3) >> 2;
        int j = 0;
        for (; j + 4 <= jq; j += 4) {
          int pk0 = __shfl(rec, j * 4 + g);
          int pk1 = __shfl(rec, j * 4 + 4 + g);
          int pk2 = __shfl(rec, j * 4 + 8 + g);
          int pk3 = __shfl(rec, j * 4 + 12 + g);
          // ABLATION: rows masked &63 -> L1-resident gather targets
          float4 a0 = inp4[(pk0 & 63) * 16 + k];
          float4 r0 = rw4[((pk0 >> 16) & 63) * 16 + k];
          float4 a1 = inp4[(pk1 & 63) * 16 + k];
          float4 r1 = rw4[((pk1 >> 16) & 63) * 16 + k];
          float4 a2 = inp4[(pk2 & 63) * 16 + k];
          float4 r2 = rw4[((pk2 >> 16) & 63) * 16 + k];
          float4 a3 = inp4[(pk3 & 63) * 16 + k];
          float4 r3 = rw4[((pk3 >> 16) & 63) * 16 + k];
          accumF(a0, r0, s4, q4);
          accumF(a1, r1, s4, q4);
          accumF(a2, r2, s4, q4);
          accumF(a3, r3, s4, q4);
        }
        for (; j < jq; ++j) {
          int pk = __shfl(rec, j * 4 + g);
          float4 a = inp4[(pk & 63) * 16 + k];
          float4 r = rw4[((pk >> 16) & 63) * 16 + k];
          accumF(a, r, s4, q4);
        }
        for (; j < jmax; ++j) {
          int slot = j * 4 + g;
          int pk = __shfl(rec, slot & 63);
          float wsel = (slot < mm) ? 1.0f : 0.0f;
          float4 a = inp4[(pk & 63) * 16 + k];
          float4 r = rw4[((pk >> 16) & 63) * 16 + k];
          float tx = a.x*r.x, ty = a.y*r.y, tz = a.z*r.z, tw = a.w*r.w;
          s4.x = fmaf(wsel, tx, s4.x); q4.x = fmaf(wsel*tx, tx, q4.x);
          s4.y = fmaf(wsel, ty, s4.y); q4.y = fmaf(wsel*ty, ty, q4.y);
          s4.z = fmaf(wsel, tz, s4.z); q4.z = fmaf(wsel*tz, tz, q4.z);
          s4.w = fmaf(wsel, tw, s4.w); q4.w = fmaf(wsel*tw, tw, q4.w);
        }
      }
    }
    s4.x += __shfl_xor(s4.x, 16); s4.x += __shfl_xor(s4.x, 32);
    s4.y += __shfl_xor(s4.y, 16); s4.y += __shfl_xor(s4.y, 32);
    s4.z += __shfl_xor(s4.z, 16); s4.z += __shfl_xor(s4.z, 32);
    s4.w += __shfl_xor(s4.w, 16); s4.w += __shfl_xor(s4.w, 32);
    q4.x += __shfl_xor(q4.x, 16); q4.x += __shfl_xor(q4.x, 32);
    q4.y += __shfl_xor(q4.y, 16); q4.y += __shfl_xor(q4.y, 32);
    q4.z += __shfl_xor(q4.z, 16); q4.z += __shfl_xor(q4.z, 32);
    q4.w += __shfl_xor(q4.w, 16); q4.w += __shfl_xor(q4.w, 32);
    if (g == 0) {
      float4 b4 = loadF4(boundary, n * 16 + k, bfB);
      float dg = degf + 1.0f;
      float sv, qv;
      bf16x4 u;
      sv = (s4.x + b4.x) / dg; qv = (q4.x + b4.x * b4.x) / dg;
      u[0] = (__bf16)sqrtf(fmaxf(qv - sv * sv, 1e-6f));
      sv = (s4.y + b4.y) / dg; qv = (q4.y + b4.y * b4.y) / dg;
      u[1] = (__bf16)sqrtf(fmaxf(qv - sv * sv, 1e-6f));
      sv = (s4.z + b4.z) / dg; qv = (q4.z + b4.z * b4.z) / dg;
      u[2] = (__bf16)sqrtf(fmaxf(qv - sv * sv, 1e-6f));
      sv = (s4.w + b4.w) / dg; qv = (q4.w + b4.w * b4.w) / dg;
      u[3] = (__bf16)sqrtf(fmaxf(qv - sv * sv, 1e-6f));
      *(bf16x4*)&updb[row][4 * k] = u;
    }
  }
  __syncthreads();

  int tt = wv >> 1, chh = wv & 1;
  bf16x8 af0 = *(const bf16x8*)&updb[tt * 16 + (ln & 15)][q * 8];
  bf16x8 af1 = *(const bf16x8*)&updb[tt * 16 + (ln & 15)][32 + q * 8];
  unsigned red = 0;
  #pragma unroll
  for (int hh = 0; hh < 2; ++hh) {
    int cc = chh * 32 + hh * 16 + (ln & 15);
    bf16x8 bfr0, bfr1;
    #pragma unroll
    for (int j = 0; j < 8; ++j) {
      bfr0[j] = (__bf16)loadF(W, cc * 64 + q * 8 + j, bfW);
      bfr1[j] = (__bf16)loadF(W, cc * 64 + 32 + q * 8 + j, bfW);
    }
    float bias = loadF(bv, cc, bfW);
    f32x4 accv = {0.f, 0.f, 0.f, 0.f};
    accv = __builtin_amdgcn_mfma_f32_16x16x32_bf16(af0, bfr0, accv, 0, 0, 0);
    accv = __builtin_amdgcn_mfma_f32_16x16x32_bf16(af1, bfr1, accv, 0, 0, 0);
    red ^= __float_as_uint(accv[0] + accv[1] + accv[2] + accv[3] + bias);
  }
  red ^= (unsigned)__shfl_xor((int)red, 1);
  red ^= (unsigned)__shfl_xor((int)red, 2);
  red ^= (unsigned)__shfl_xor((int)red, 4);
  red ^= (unsigned)__shfl_xor((int)red, 8);
  red ^= (unsigned)__shfl_xor((int)red, 16);
  red ^= (unsigned)__shfl_xor((int)red, 32);
  if (ln == 0)
    atomicOr(&bcurp[(blockIdx.x % NBK) * 16 + 8], (int)red);
}

extern "C" void kernel_launch(void* const* d_in, const int* in_sizes, int n_in,
                              void* d_out, int out_size, void* d_ws, size_t ws_size,
                              hipStream_t stream) {
  const void* input    = d_in[0];
  const void* boundary = d_in[1];
  const int*  edges    = (const int*)d_in[2];
  const void* eweight  = d_in[3];
  const void* relw     = d_in[4];
  const void* W        = d_in[5];
  const void* bv       = d_in[6];

  int* wsI    = (int*)d_ws;
  int* flags  = wsI + OFF_FLAGS;
  int* bcurp  = wsI + OFF_BCURP;
  int* eidx   = wsI + OFF_EIDX;

  long avail = (long)(ws_size / 4) - OFF_EIDX;
  if (avail < 1) avail = 1;
  int padcap = 8192;
  long bfit = avail / padcap;
  if (bfit < 1) { padcap = (int)avail; bfit = 1; }
  if (bfit > NBK) bfit = NBK;
  int npass = (int)((NBK + bfit - 1) / bfit);

  k_detect<<<1, 64, 0, stream>>>(input, boundary, relw, W, eweight,
                                 flags, bcurp);
  k_ew<<<(NE + 8191) / 8192, 256, 0, stream>>>(eweight, flags);

  const int PA_NB = (NE + CHUNK - 1) / CHUNK;
  for (int p = 0; p < npass; ++p) {
    int gb0 = (int)((long)NBK * p / npass);
    int gb1 = (int)((long)NBK * (p + 1) / npass);
    int hi = (gb1 * 128 < NN) ? gb1 * 128 : NN;
    k_parta<<<PA_NB, 1024, 0, stream>>>(edges, bcurp, eidx, flags,
                                        gb0, gb1, padcap);
    k_node<<<(gb1 - gb0) * 4, 256, 0, stream>>>(
        input, boundary, edges, eweight, relw, W, bv, bcurp, eidx, flags,
        d_out, gb0, hi, padcap);
  }
  // Sacrificial ablation probe (only when the full graph fits one pass):
  // measures the k_node instruction stream with L1-resident gathers.
  if (npass == 1) {
    k_probe<<<NBK * 4, 256, 0, stream>>>(
        input, boundary, relw, W, bv, bcurp, eidx, flags, 0, NN, padcap);
  }
}

// Round 13
// 235.011 us; speedup vs baseline: 1.1823x; 1.1823x over previous
//
#include <hip/hip_runtime.h>
#include <hip/hip_bf16.h>

#define NN   50000
#define NE   1600000
#define DIM  64
#define NB32 1563        // 32-node buckets (nout>>5), max idx 1562

// ---- ws layout (int32 offsets) -------------------------------------------
#define OFF_FLAGS  0            // 8 ints
#define OFF_BCUR   8            // 1563*4 cursors (16B stride)
#define OFF_EIDX   6264         // padded records: [bucket][PADCAP]

#define CHUNK  4096  // edges per k_parta block
#define PADCAP 2048  // region ints per 32-node bucket (expected max ~1200)

typedef __bf16 bf16x8 __attribute__((ext_vector_type(8)));
typedef __bf16 bf16x4 __attribute__((ext_vector_type(4)));
typedef float  f32x4  __attribute__((ext_vector_type(4)));

__device__ __forceinline__ float loadF(const void* p, int i, int bf) {
  if (bf) return __bfloat162float(((const __hip_bfloat16*)p)[i]);
  return ((const float*)p)[i];
}

__device__ __forceinline__ float4 loadF4(const void* p, int i4, int bf) {
  if (bf) {
    ushort4 u = ((const ushort4*)p)[i4];
    float4 f;
    union { unsigned int ui; float fl; } c;
    c.ui = (unsigned int)u.x << 16; f.x = c.fl;
    c.ui = (unsigned int)u.y << 16; f.y = c.fl;
    c.ui = (unsigned int)u.z << 16; f.z = c.fl;
    c.ui = (unsigned int)u.w << 16; f.w = c.fl;
    return f;
  }
  return ((const float4*)p)[i4];
}

__device__ __forceinline__ void accumF(float4 a, float4 r,
                                       float4& s4, float4& q4) {
  float tx = a.x * r.x, ty = a.y * r.y, tz = a.z * r.z, tw = a.w * r.w;
  s4.x += tx; q4.x = fmaf(tx, tx, q4.x);
  s4.y += ty; q4.y = fmaf(ty, ty, q4.y);
  s4.z += tz; q4.z = fmaf(tz, tz, q4.z);
  s4.w += tw; q4.w = fmaf(tw, tw, q4.w);
}

// Per-array dtype detection + zero bucket cursors.
__global__ void k_detect(const void* input, const void* boundary,
                         const void* relw, const void* W, const void* ew,
                         int* flags, int* bcur) {
  __shared__ int cnt;
  int t = threadIdx.x;  // 64 threads
  const void* arrs[4] = {input, boundary, relw, W};
  for (int a = 0; a < 4; ++a) {
    if (t == 0) cnt = 0;
    __syncthreads();
    const unsigned short* u = (const unsigned short*)arrs[a];
    unsigned ex = (u[2 * t] >> 7) & 0xFF;
    if (ex >= 100 && ex <= 140) atomicAdd(&cnt, 1);
    __syncthreads();
    if (t == 0) flags[a] = (cnt >= 32) ? 1 : 0;
    __syncthreads();
  }
  if (t == 0) {
    flags[4] = (((const unsigned short*)ew)[0] == 0x3F80) ? 1 : 0;
    flags[5] = 1;
  }
  for (int i = t; i < NB32 * 4; i += 64) bcur[i] = 0;
}

// Exact all-ones check of edge weights.
__global__ __launch_bounds__(256) void k_ew(const void* __restrict__ ew,
                                            int* __restrict__ flags) {
  int bfE = flags[4];
  int c0 = blockIdx.x * 8192;
  int bad = 0;
  for (int i = threadIdx.x; i < 8192; i += 256) {
    int e = c0 + i;
    if (e < NE && loadF(ew, e, bfE) != 1.0f) bad = 1;
  }
  if (bad) flags[5] = 0;
}

// Partition edges into PADDED per-32-node-bucket regions via LDS staging.
// R13: single-atomic-pass -- the pass-1 histogram atomic also yields the
// record's rank (R12 probe: the 2nd LDS-atomic pass was pure overhead).
// rec = nin|rel<<16|local5<<25 (ones) or e|local5<<25 (generic).
__global__ __launch_bounds__(1024) void k_parta(
    const int* __restrict__ el, int* __restrict__ bcur,
    int* __restrict__ eidx, const int* __restrict__ flags,
    int gb0, int gb1, int padcap) {
  __shared__ int stage[CHUNK];              // 16 KB
  __shared__ unsigned short sbk[CHUNK];     // 8 KB
  __shared__ int lh[NB32], lbase[NB32], gbs[NB32];   // 18.8 KB
  __shared__ int sc[256];
  __shared__ int total;
  int t = threadIdx.x;
  int nb = gb1 - gb0;
  int c0 = blockIdx.x * CHUNK;
  int ones = flags[5];
  for (int i = t; i < nb; i += 1024) lh[i] = 0;
  __syncthreads();

  // pass 1: load triples once; histogram atomic doubles as rank.
  int rec[4], bb[4], rk[4];
  #pragma unroll
  for (int j = 0; j < 4; ++j) {
    int e = c0 + j * 1024 + t;
    bb[j] = -1; rec[j] = 0; rk[j] = 0;
    if (e < NE) {
      int n0 = el[e * 3], n1 = el[e * 3 + 1], n2 = el[e * 3 + 2];
      int b = (n1 >> 5) - gb0;
      if (b >= 0 && b < nb) {
        bb[j] = b;
        rec[j] = ones ? (n0 | (n2 << 16) | ((n1 & 31) << 25))
                      : (e | ((n1 & 31) << 25));
        rk[j] = atomicAdd(&lh[b], 1);
      }
    }
  }
  __syncthreads();

  // two-level scan of up to 1563 bin counts: 7 bins/thread serial + block
  // scan of 256 partials; also grab global cursors per non-empty bin.
  int v[7]; int s = 0;
  int base = t * 7;
  #pragma unroll
  for (int j = 0; j < 7; ++j) {
    int idx = base + j;
    v[j] = (idx < nb) ? lh[idx] : 0;
    s += v[j];
  }
  sc[t < 256 ? t : 255] = 0;   // only first 256 threads own sc
  __syncthreads();
  if (t < 256) sc[t] = s;
  __syncthreads();
  for (int off = 1; off < 256; off <<= 1) {
    int x = 0;
    if (t < 256 && t >= off) x = sc[t - off];
    __syncthreads();
    if (t < 256) sc[t] += x;
    __syncthreads();
  }
  {
    int excl = (t < 256) ? (sc[t] - s) : 0;
    #pragma unroll
    for (int j = 0; j < 7; ++j) {
      int idx = base + j;
      if (idx < nb) {
        lbase[idx] = excl;
        if (v[j] > 0)
          gbs[idx] = atomicAdd(&bcur[(gb0 + idx) * 4], v[j]);
        excl += v[j];
      }
    }
    if (t == 255) total = sc[255];
  }
  __syncthreads();

  // pass 2: pure LDS writes at precomputed slots (no atomics).
  #pragma unroll
  for (int j = 0; j < 4; ++j) {
    if (bb[j] >= 0) {
      int slot = lbase[bb[j]] + rk[j];
      stage[slot] = rec[j];
      sbk[slot] = (unsigned short)bb[j];
    }
  }
  __syncthreads();

  // pass 3: coalesced run-writes to padded global regions.
  int tot = total;
  for (int i = t; i < tot; i += 1024) {
    int b = sbk[i];
    int slot = gbs[b] + (i - lbase[b]);
    if (slot < padcap) eidx[(long)b * padcap + slot] = stage[i];
  }
}

// R13 k_node: one block = one 32-node bucket (grid = NB32, 256 threads,
// ~17 KB LDS -> 8 blocks/CU). No quarter-filter pass (R12 probe showed the
// 4x-redundant filter+LDS-atomic structure was the dominant cost slice):
// records load directly, sort over 32 bins, then the proven edge phase.
__global__ __launch_bounds__(256, 8) void k_node(
    const void* __restrict__ input, const void* __restrict__ boundary,
    const int* __restrict__ el, const void* __restrict__ ew,
    const void* __restrict__ relw, const void* __restrict__ W,
    const void* __restrict__ bv, const int* __restrict__ bcur,
    const int* __restrict__ eidx, const int* __restrict__ flags,
    void* __restrict__ out, int gb0, int hi, int padcap) {
  __shared__ int ld[PADCAP];     // raw records; aliased as updb later
  __shared__ int ld2[PADCAP];    // node-sorted records
  __shared__ int lstart[32], lend[32], lcnt[32];
  __bf16 (*updb)[72] = reinterpret_cast<__bf16(*)[72]>(ld);

  int bfI = flags[0], bfB = flags[1], bfR = flags[2], bfW = flags[3],
      bfE = flags[4], ones = flags[5];
  int t = threadIdx.x;
  int wv = t >> 6, ln = t & 63;
  int g = ln >> 4;
  int k = ln & 15;
  int q = ln >> 4;
  int B = gb0 + blockIdx.x;
  int n0 = B * 32;
  int cnt = bcur[B * 4];
  int fast = (cnt <= padcap);
  const int* myeidx = eidx + (long)blockIdx.x * padcap;

  if (t < 32) lcnt[t] = 0;
  __syncthreads();
  int cl = cnt < padcap ? cnt : padcap;
  if (fast) {
    for (int i = t; i < cl; i += 256) ld[i] = myeidx[i];
    __syncthreads();
    for (int i = t; i < cl; i += 256)
      atomicAdd(&lcnt[(((unsigned)ld[i]) >> 25) & 31], 1);
  }
  __syncthreads();
  if (t < 32) lend[t] = lcnt[t];
  __syncthreads();
  for (int off = 1; off < 32; off <<= 1) {
    int v = 0;
    if (t < 32 && t >= off) v = lend[t - off];
    __syncthreads();
    if (t < 32) lend[t] += v;
    __syncthreads();
  }
  if (t < 32) { lstart[t] = lend[t] - lcnt[t]; lcnt[t] = 0; }
  __syncthreads();
  if (fast) {
    for (int i = t; i < cl; i += 256) {
      int rc = ld[i];
      int l = (((unsigned)rc) >> 25) & 31;
      int r = atomicAdd(&lcnt[l], 1);
      ld2[lstart[l] + r] = rc;
    }
  }
  __syncthreads();   // ld dead from here -> safe to alias as updb

  const float4* inp4 = (const float4*)input;
  const float4* rw4  = (const float4*)relw;
  int hot = (!bfI && !bfR && ones) ? 1 : 0;

  // ---- edge phase: 8 nodes per wave (4 waves x 8 = 32 nodes) ----
  for (int rr = 0; rr < 8; ++rr) {
    int row = wv * 8 + rr;
    int n = n0 + row;
    if (n >= hi) {
      if (g == 0) *(bf16x4*)&updb[row][4 * k] =
          bf16x4{(__bf16)0.f, (__bf16)0.f, (__bf16)0.f, (__bf16)0.f};
      continue;
    }
    float4 s4 = {0.f,0.f,0.f,0.f}, q4 = {0.f,0.f,0.f,0.f};
    float degf = 0.f;
    if (fast) {
      int start = lstart[row], end = lend[row];
      degf = (float)(end - start);
      if (hot) {
        for (int base = start; base < end; base += 64) {
          int mm = end - base; if (mm > 64) mm = 64;
          int rec = 0;
          if (ln < mm) rec = ld2[base + ln];
          int jq = mm >> 2;
          int jmax = (mm + 3) >> 2;
          int j = 0;
          for (; j + 4 <= jq; j += 4) {
            int pk0 = __shfl(rec, j * 4 + g);
            int pk1 = __shfl(rec, j * 4 + 4 + g);
            int pk2 = __shfl(rec, j * 4 + 8 + g);
            int pk3 = __shfl(rec, j * 4 + 12 + g);
            float4 a0 = inp4[(pk0 & 0xFFFF) * 16 + k];
            float4 r0 = rw4[((pk0 >> 16) & 0x1FF) * 16 + k];
            float4 a1 = inp4[(pk1 & 0xFFFF) * 16 + k];
            float4 r1 = rw4[((pk1 >> 16) & 0x1FF) * 16 + k];
            float4 a2 = inp4[(pk2 & 0xFFFF) * 16 + k];
            float4 r2 = rw4[((pk2 >> 16) & 0x1FF) * 16 + k];
            float4 a3 = inp4[(pk3 & 0xFFFF) * 16 + k];
            float4 r3 = rw4[((pk3 >> 16) & 0x1FF) * 16 + k];
            accumF(a0, r0, s4, q4);
            accumF(a1, r1, s4, q4);
            accumF(a2, r2, s4, q4);
            accumF(a3, r3, s4, q4);
          }
          for (; j < jq; ++j) {
            int pk = __shfl(rec, j * 4 + g);
            float4 a = inp4[(pk & 0xFFFF) * 16 + k];
            float4 r = rw4[((pk >> 16) & 0x1FF) * 16 + k];
            accumF(a, r, s4, q4);
          }
          for (; j < jmax; ++j) {
            int slot = j * 4 + g;
            int pk = __shfl(rec, slot & 63);
            float wsel = (slot < mm) ? 1.0f : 0.0f;
            float4 a = inp4[(pk & 0xFFFF) * 16 + k];
            float4 r = rw4[((pk >> 16) & 0x1FF) * 16 + k];
            float tx = a.x*r.x, ty = a.y*r.y, tz = a.z*r.z, tw = a.w*r.w;
            s4.x = fmaf(wsel, tx, s4.x); q4.x = fmaf(wsel*tx, tx, q4.x);
            s4.y = fmaf(wsel, ty, s4.y); q4.y = fmaf(wsel*ty, ty, q4.y);
            s4.z = fmaf(wsel, tz, s4.z); q4.z = fmaf(wsel*tz, tz, q4.z);
            s4.w = fmaf(wsel, tw, s4.w); q4.w = fmaf(wsel*tw, tw, q4.w);
          }
        }
      } else {
        for (int base = start; base < end; base += 64) {
          int mm = end - base; if (mm > 64) mm = 64;
          int rec = 0; float wrec = 0.0f;
          if (ln < mm) {
            rec = ld2[base + ln] & 0x1FFFFFF;
            if (!ones) wrec = loadF(ew, rec, bfE);
          }
          int jmax = (mm + 3) >> 2;
          for (int j = 0; j < jmax; ++j) {
            int slot = j * 4 + g;
            int rj = __shfl(rec, slot);
            int nin, rl; float wj;
            if (ones) { nin = rj & 0xFFFF; rl = (rj >> 16) & 0x1FF; wj = 1.0f; }
            else      { nin = el[rj * 3]; rl = el[rj * 3 + 2];
                        wj = __shfl(wrec, slot); }
            float wsel = (slot < mm) ? wj : 0.0f;
            float4 a = loadF4(input, nin * 16 + k, bfI);
            float4 r = loadF4(relw, rl * 16 + k, bfR);
            float tx = a.x*r.x, ty = a.y*r.y, tz = a.z*r.z, tw = a.w*r.w;
            s4.x = fmaf(wsel, tx, s4.x); q4.x = fmaf(wsel*tx, tx, q4.x);
            s4.y = fmaf(wsel, ty, s4.y); q4.y = fmaf(wsel*ty, ty, q4.y);
            s4.z = fmaf(wsel, tz, s4.z); q4.z = fmaf(wsel*tz, tz, q4.z);
            s4.w = fmaf(wsel, tw, s4.w); q4.w = fmaf(wsel*tw, tw, q4.w);
          }
        }
      }
    } else {
      // correctness-only fallback: scan full edge list for this node
      float degc = 0.f;
      for (int e0 = g; e0 < NE; e0 += 4) {
        int nout = el[e0 * 3 + 1];
        if (nout != n) continue;
        degc += 1.0f;
        int nin = el[e0 * 3], rl = el[e0 * 3 + 2];
        float wj = ones ? 1.0f : loadF(ew, e0, bfE);
        float4 a = loadF4(input, nin * 16 + k, bfI);
        float4 r = loadF4(relw, rl * 16 + k, bfR);
        float tx = wj*a.x*r.x, ty = wj*a.y*r.y, tz = wj*a.z*r.z,
              tw = wj*a.w*r.w;
        s4.x += tx; q4.x = fmaf(tx, tx, q4.x);
        s4.y += ty; q4.y = fmaf(ty, ty, q4.y);
        s4.z += tz; q4.z = fmaf(tz, tz, q4.z);
        s4.w += tw; q4.w = fmaf(tw, tw, q4.w);
      }
      degc += __shfl_xor(degc, 16); degc += __shfl_xor(degc, 32);
      degf = degc;
    }
    s4.x += __shfl_xor(s4.x, 16); s4.x += __shfl_xor(s4.x, 32);
    s4.y += __shfl_xor(s4.y, 16); s4.y += __shfl_xor(s4.y, 32);
    s4.z += __shfl_xor(s4.z, 16); s4.z += __shfl_xor(s4.z, 32);
    s4.w += __shfl_xor(s4.w, 16); s4.w += __shfl_xor(s4.w, 32);
    q4.x += __shfl_xor(q4.x, 16); q4.x += __shfl_xor(q4.x, 32);
    q4.y += __shfl_xor(q4.y, 16); q4.y += __shfl_xor(q4.y, 32);
    q4.z += __shfl_xor(q4.z, 16); q4.z += __shfl_xor(q4.z, 32);
    q4.w += __shfl_xor(q4.w, 16); q4.w += __shfl_xor(q4.w, 32);
    if (g == 0) {
      float4 b4 = loadF4(boundary, n * 16 + k, bfB);
      float dg = degf + 1.0f;
      float sv, qv;
      bf16x4 u;
      sv = (s4.x + b4.x) / dg; qv = (q4.x + b4.x * b4.x) / dg;
      u[0] = (__bf16)sqrtf(fmaxf(qv - sv * sv, 1e-6f));
      sv = (s4.y + b4.y) / dg; qv = (q4.y + b4.y * b4.y) / dg;
      u[1] = (__bf16)sqrtf(fmaxf(qv - sv * sv, 1e-6f));
      sv = (s4.z + b4.z) / dg; qv = (q4.z + b4.z * b4.z) / dg;
      u[2] = (__bf16)sqrtf(fmaxf(qv - sv * sv, 1e-6f));
      sv = (s4.w + b4.w) / dg; qv = (q4.w + b4.w * b4.w) / dg;
      u[3] = (__bf16)sqrtf(fmaxf(qv - sv * sv, 1e-6f));
      *(bf16x4*)&updb[row][4 * k] = u;
    }
  }
  __syncthreads();

  // ---- MFMA epilogue: 4 waves, 2 tiles; wave wv -> tile wv>>1, half wv&1 --
  int tt = wv >> 1, chh = wv & 1;
  bf16x8 af0 = *(const bf16x8*)&updb[tt * 16 + (ln & 15)][q * 8];
  bf16x8 af1 = *(const bf16x8*)&updb[tt * 16 + (ln & 15)][32 + q * 8];
  #pragma unroll
  for (int hh = 0; hh < 2; ++hh) {
    int cc = chh * 32 + hh * 16 + (ln & 15);
    bf16x8 bfr0, bfr1;
    #pragma unroll
    for (int j = 0; j < 8; ++j) {
      bfr0[j] = (__bf16)loadF(W, cc * 64 + q * 8 + j, bfW);
      bfr1[j] = (__bf16)loadF(W, cc * 64 + 32 + q * 8 + j, bfW);
    }
    float bias = loadF(bv, cc, bfW);
    f32x4 accv = {0.f, 0.f, 0.f, 0.f};
    accv = __builtin_amdgcn_mfma_f32_16x16x32_bf16(af0, bfr0, accv, 0, 0, 0);
    accv = __builtin_amdgcn_mfma_f32_16x16x32_bf16(af1, bfr1, accv, 0, 0, 0);
    #pragma unroll
    for (int i = 0; i < 4; ++i) {
      int nn = n0 + tt * 16 + q * 4 + i;
      if (nn < hi) {
        float v = accv[i] + bias;
        if (bfI) ((__hip_bfloat16*)out)[nn * 64 + cc] = __float2bfloat16(v);
        else     ((float*)out)[nn * 64 + cc] = v;
      }
    }
  }
}

extern "C" void kernel_launch(void* const* d_in, const int* in_sizes, int n_in,
                              void* d_out, int out_size, void* d_ws, size_t ws_size,
                              hipStream_t stream) {
  const void* input    = d_in[0];
  const void* boundary = d_in[1];
  const int*  edges    = (const int*)d_in[2];
  const void* eweight  = d_in[3];
  const void* relw     = d_in[4];
  const void* W        = d_in[5];
  const void* bv       = d_in[6];

  int* wsI    = (int*)d_ws;
  int* flags  = wsI + OFF_FLAGS;
  int* bcur   = wsI + OFF_BCUR;
  int* eidx   = wsI + OFF_EIDX;

  long avail = (long)(ws_size / 4) - OFF_EIDX;
  if (avail < 1) avail = 1;
  int padcap = PADCAP;
  long bfit = avail / padcap;
  if (bfit < 1) { padcap = (int)avail; bfit = 1; }
  if (bfit > NB32) bfit = NB32;
  int npass = (int)((NB32 + bfit - 1) / bfit);

  k_detect<<<1, 64, 0, stream>>>(input, boundary, relw, W, eweight,
                                 flags, bcur);
  k_ew<<<(NE + 8191) / 8192, 256, 0, stream>>>(eweight, flags);

  const int PA_NB = (NE + CHUNK - 1) / CHUNK;
  for (int p = 0; p < npass; ++p) {
    int gb0 = (int)((long)NB32 * p / npass);
    int gb1 = (int)((long)NB32 * (p + 1) / npass);
    int hi = (gb1 * 32 < NN) ? gb1 * 32 : NN;
    k_parta<<<PA_NB, 1024, 0, stream>>>(edges, bcur, eidx, flags,
                                        gb0, gb1, padcap);
    k_node<<<gb1 - gb0, 256, 0, stream>>>(
        input, boundary, edges, eweight, relw, W, bv, bcur, eidx, flags,
        d_out, gb0, hi, padcap);
  }
}

// Round 14
// 210.934 us; speedup vs baseline: 1.3173x; 1.1141x over previous
//
#include <hip/hip_runtime.h>
#include <hip/hip_bf16.h>

#define NN  50000
#define NE  1600000
#define DIM 64
#define NBK 391          // 128-node buckets

// ---- ws layout (int32 offsets) -------------------------------------------
#define OFF_FLAGS  0            // 8 ints
#define OFF_BCURP  8            // 391*16 padded cursors (64B/bucket, atomics)
#define OFF_EIDX   6272         // padded records: [bucket][PADCAP]

#define CHUNK 8192   // edges per k_parta block (runs ~21 ints: keep 391 bins)
#define QCAP  2304   // per-quarter record capacity in k_node

typedef __bf16 bf16x8 __attribute__((ext_vector_type(8)));
typedef __bf16 bf16x4 __attribute__((ext_vector_type(4)));
typedef float  f32x4  __attribute__((ext_vector_type(4)));

__device__ __forceinline__ float loadF(const void* p, int i, int bf) {
  if (bf) return __bfloat162float(((const __hip_bfloat16*)p)[i]);
  return ((const float*)p)[i];
}

__device__ __forceinline__ float4 loadF4(const void* p, int i4, int bf) {
  if (bf) {
    ushort4 u = ((const ushort4*)p)[i4];
    float4 f;
    union { unsigned int ui; float fl; } c;
    c.ui = (unsigned int)u.x << 16; f.x = c.fl;
    c.ui = (unsigned int)u.y << 16; f.y = c.fl;
    c.ui = (unsigned int)u.z << 16; f.z = c.fl;
    c.ui = (unsigned int)u.w << 16; f.w = c.fl;
    return f;
  }
  return ((const float4*)p)[i4];
}

__device__ __forceinline__ void accumF(float4 a, float4 r,
                                       float4& s4, float4& q4) {
  float tx = a.x * r.x, ty = a.y * r.y, tz = a.z * r.z, tw = a.w * r.w;
  s4.x += tx; q4.x = fmaf(tx, tx, q4.x);
  s4.y += ty; q4.y = fmaf(ty, ty, q4.y);
  s4.z += tz; q4.z = fmaf(tz, tz, q4.z);
  s4.w += tw; q4.w = fmaf(tw, tw, q4.w);
}

// Per-array dtype detection + zero padded bucket cursors.
__global__ void k_detect(const void* input, const void* boundary,
                         const void* relw, const void* W, const void* ew,
                         int* flags, int* bcurp) {
  __shared__ int cnt;
  int t = threadIdx.x;  // 64 threads
  const void* arrs[4] = {input, boundary, relw, W};
  for (int a = 0; a < 4; ++a) {
    if (t == 0) cnt = 0;
    __syncthreads();
    const unsigned short* u = (const unsigned short*)arrs[a];
    unsigned ex = (u[2 * t] >> 7) & 0xFF;
    if (ex >= 100 && ex <= 140) atomicAdd(&cnt, 1);
    __syncthreads();
    if (t == 0) flags[a] = (cnt >= 32) ? 1 : 0;
    __syncthreads();
  }
  if (t == 0) {
    flags[4] = (((const unsigned short*)ew)[0] == 0x3F80) ? 1 : 0;
    flags[5] = 1;
  }
  for (int i = t; i < NBK * 16; i += 64) bcurp[i] = 0;
}

// Exact all-ones check of edge weights.
__global__ __launch_bounds__(256) void k_ew(const void* __restrict__ ew,
                                            int* __restrict__ flags) {
  int bfE = flags[4];
  int c0 = blockIdx.x * 8192;
  int bad = 0;
  for (int i = threadIdx.x; i < 8192; i += 256) {
    int e = c0 + i;
    if (e < NE && loadF(ew, e, bfE) != 1.0f) bad = 1;
  }
  if (bad) flags[5] = 0;
}

// Partition edges into PADDED per-bucket regions via LDS staging.
// R14: R11 geometry (391 bins, CHUNK 8192 -> write-runs ~21 ints) with the
// single-atomic-pass trick: the pass-1 histogram atomic also yields each
// record's rank, deleting the second 8192-LDS-atomic pass (lh2) per block.
__global__ __launch_bounds__(1024) void k_parta(
    const int* __restrict__ el, int* __restrict__ bcurp,
    int* __restrict__ eidx, const int* __restrict__ flags,
    int gb0, int gb1, int padcap) {
  __shared__ int stage[CHUNK];              // 32 KB
  __shared__ unsigned short sbk[CHUNK];     // 16 KB
  __shared__ int lh[NBK], lbase[NBK], gbs[NBK];
  __shared__ int sc[256];
  __shared__ int total;
  int t = threadIdx.x;
  int nb = gb1 - gb0;
  int c0 = blockIdx.x * CHUNK;
  int ones = flags[5];
  for (int i = t; i < nb; i += 1024) lh[i] = 0;
  __syncthreads();

  // pass 1: load triples once; histogram atomic doubles as rank.
  int rec[8], bb[8], rk[8];
  #pragma unroll
  for (int j = 0; j < 8; ++j) {
    int e = c0 + j * 1024 + t;
    bb[j] = -1; rec[j] = 0; rk[j] = 0;
    if (e < NE) {
      int n0 = el[e * 3], n1 = el[e * 3 + 1], n2 = el[e * 3 + 2];
      int b = (n1 >> 7) - gb0;
      if (b >= 0 && b < nb) {
        bb[j] = b;
        rec[j] = ones ? (n0 | (n2 << 16) | ((n1 & 127) << 25))
                      : (e | ((n1 & 127) << 25));
        rk[j] = atomicAdd(&lh[b], 1);
      }
    }
  }
  __syncthreads();

  // scan (pair trick, first 256 threads), cursor atomics.
  int a0 = 0, a1 = 0;
  if (t < 256) {
    a0 = (2 * t < nb) ? lh[2 * t] : 0;
    a1 = (2 * t + 1 < nb) ? lh[2 * t + 1] : 0;
    sc[t] = a0 + a1;
  }
  __syncthreads();
  for (int off = 1; off < 256; off <<= 1) {
    int v = 0;
    if (t < 256 && t >= off) v = sc[t - off];
    __syncthreads();
    if (t < 256) sc[t] += v;
    __syncthreads();
  }
  if (t < 256) {
    int excl = sc[t] - (a0 + a1);
    if (2 * t < nb) {
      lbase[2 * t] = excl;
      if (a0 > 0) gbs[2 * t] = atomicAdd(&bcurp[(gb0 + 2 * t) * 16], a0);
    }
    if (2 * t + 1 < nb) {
      lbase[2 * t + 1] = excl + a0;
      if (a1 > 0)
        gbs[2 * t + 1] = atomicAdd(&bcurp[(gb0 + 2 * t + 1) * 16], a1);
    }
    if (t == 255) total = sc[255];
  }
  __syncthreads();

  // pass 2: pure LDS writes at precomputed slots (no atomics).
  #pragma unroll
  for (int j = 0; j < 8; ++j) {
    if (bb[j] >= 0) {
      int slot = lbase[bb[j]] + rk[j];
      stage[slot] = rec[j];
      sbk[slot] = (unsigned short)bb[j];
    }
  }
  __syncthreads();

  // pass 3: coalesced run-writes to padded global regions.
  int tot = total;
  for (int i = t; i < tot; i += 1024) {
    int b = sbk[i];
    int slot = gbs[b] + (i - lbase[b]);
    if (slot < padcap) eidx[(long)b * padcap + slot] = stage[i];
  }
}

// R11 k_node (95.8us verified): quarter-split fused sort+node. 4 blocks per
// 128-node bucket, 256 threads, ~19 KB LDS -> 8 blocks/CU all-resident.
__global__ __launch_bounds__(256, 8) void k_node(
    const void* __restrict__ input, const void* __restrict__ boundary,
    const int* __restrict__ el, const void* __restrict__ ew,
    const void* __restrict__ relw, const void* __restrict__ W,
    const void* __restrict__ bv, const int* __restrict__ bcurp,
    const int* __restrict__ eidx, const int* __restrict__ flags,
    void* __restrict__ out, int gb0, int hi, int padcap) {
  __shared__ int ld[QCAP];
  __shared__ int ld2[QCAP];
  __shared__ int lstart[32], lend[32], lcnt[32];
  __shared__ int nf, ovf;
  __bf16 (*updb)[72] = reinterpret_cast<__bf16(*)[72]>(ld);

  int bfI = flags[0], bfB = flags[1], bfR = flags[2], bfW = flags[3],
      bfE = flags[4], ones = flags[5];
  int t = threadIdx.x;
  int wv = t >> 6, ln = t & 63;
  int g = ln >> 4;
  int k = ln & 15;
  int q = ln >> 4;
  int Bl = blockIdx.x >> 2;
  int B  = gb0 + Bl;
  int quarter = blockIdx.x & 3;
  int n0 = B * 128 + quarter * 32;
  int cnt = bcurp[B * 16];
  const int* myeidx = eidx + (long)Bl * padcap;

  if (t == 0) { nf = 0; ovf = (cnt > padcap) ? 1 : 0; }
  if (t < 32) lcnt[t] = 0;
  __syncthreads();

  int cl = cnt < padcap ? cnt : padcap;
  for (int i = t; i < cl; i += 256) {
    int rc = myeidx[i];
    if ((((unsigned)rc) >> 30) == (unsigned)quarter) {
      int p = atomicAdd(&nf, 1);
      if (p < QCAP) ld[p] = rc; else ovf = 1;
    }
  }
  __syncthreads();
  int fast = !ovf;
  int nq = nf < QCAP ? nf : QCAP;

  if (fast) {
    for (int i = t; i < nq; i += 256)
      atomicAdd(&lcnt[(((unsigned)ld[i]) >> 25) & 31], 1);
  }
  __syncthreads();
  if (t < 32) lend[t] = lcnt[t];
  __syncthreads();
  for (int off = 1; off < 32; off <<= 1) {
    int v = 0;
    if (t < 32 && t >= off) v = lend[t - off];
    __syncthreads();
    if (t < 32) lend[t] += v;
    __syncthreads();
  }
  if (t < 32) { lstart[t] = lend[t] - lcnt[t]; lcnt[t] = 0; }
  __syncthreads();
  if (fast) {
    for (int i = t; i < nq; i += 256) {
      int rc = ld[i];
      int l = (((unsigned)rc) >> 25) & 31;
      int r = atomicAdd(&lcnt[l], 1);
      ld2[lstart[l] + r] = rc;
    }
  }
  __syncthreads();

  const float4* inp4 = (const float4*)input;
  const float4* rw4  = (const float4*)relw;
  int hot = (!bfI && !bfR && ones) ? 1 : 0;

  for (int rr = 0; rr < 8; ++rr) {
    int row = wv * 8 + rr;
    int n = n0 + row;
    if (n >= hi) {
      if (g == 0) *(bf16x4*)&updb[row][4 * k] =
          bf16x4{(__bf16)0.f, (__bf16)0.f, (__bf16)0.f, (__bf16)0.f};
      continue;
    }
    float4 s4 = {0.f,0.f,0.f,0.f}, q4 = {0.f,0.f,0.f,0.f};
    float degf = 0.f;
    if (fast) {
      int start = lstart[row], end = lend[row];
      degf = (float)(end - start);
      if (hot) {
        for (int base = start; base < end; base += 64) {
          int mm = end - base; if (mm > 64) mm = 64;
          int rec = 0;
          if (ln < mm) rec = ld2[base + ln];
          int jq = mm >> 2;
          int jmax = (mm + 3) >> 2;
          int j = 0;
          for (; j + 4 <= jq; j += 4) {
            int pk0 = __shfl(rec, j * 4 + g);
            int pk1 = __shfl(rec, j * 4 + 4 + g);
            int pk2 = __shfl(rec, j * 4 + 8 + g);
            int pk3 = __shfl(rec, j * 4 + 12 + g);
            float4 a0 = inp4[(pk0 & 0xFFFF) * 16 + k];
            float4 r0 = rw4[((pk0 >> 16) & 0x1FF) * 16 + k];
            float4 a1 = inp4[(pk1 & 0xFFFF) * 16 + k];
            float4 r1 = rw4[((pk1 >> 16) & 0x1FF) * 16 + k];
            float4 a2 = inp4[(pk2 & 0xFFFF) * 16 + k];
            float4 r2 = rw4[((pk2 >> 16) & 0x1FF) * 16 + k];
            float4 a3 = inp4[(pk3 & 0xFFFF) * 16 + k];
            float4 r3 = rw4[((pk3 >> 16) & 0x1FF) * 16 + k];
            accumF(a0, r0, s4, q4);
            accumF(a1, r1, s4, q4);
            accumF(a2, r2, s4, q4);
            accumF(a3, r3, s4, q4);
          }
          for (; j < jq; ++j) {
            int pk = __shfl(rec, j * 4 + g);
            float4 a = inp4[(pk & 0xFFFF) * 16 + k];
            float4 r = rw4[((pk >> 16) & 0x1FF) * 16 + k];
            accumF(a, r, s4, q4);
          }
          for (; j < jmax; ++j) {
            int slot = j * 4 + g;
            int pk = __shfl(rec, slot & 63);
            float wsel = (slot < mm) ? 1.0f : 0.0f;
            float4 a = inp4[(pk & 0xFFFF) * 16 + k];
            float4 r = rw4[((pk >> 16) & 0x1FF) * 16 + k];
            float tx = a.x*r.x, ty = a.y*r.y, tz = a.z*r.z, tw = a.w*r.w;
            s4.x = fmaf(wsel, tx, s4.x); q4.x = fmaf(wsel*tx, tx, q4.x);
            s4.y = fmaf(wsel, ty, s4.y); q4.y = fmaf(wsel*ty, ty, q4.y);
            s4.z = fmaf(wsel, tz, s4.z); q4.z = fmaf(wsel*tz, tz, q4.z);
            s4.w = fmaf(wsel, tw, s4.w); q4.w = fmaf(wsel*tw, tw, q4.w);
          }
        }
      } else {
        for (int base = start; base < end; base += 64) {
          int mm = end - base; if (mm > 64) mm = 64;
          int rec = 0; float wrec = 0.0f;
          if (ln < mm) {
            rec = ld2[base + ln] & 0x1FFFFFF;
            if (!ones) wrec = loadF(ew, rec, bfE);
          }
          int jmax = (mm + 3) >> 2;
          for (int j = 0; j < jmax; ++j) {
            int slot = j * 4 + g;
            int rj = __shfl(rec, slot);
            int nin, rl; float wj;
            if (ones) { nin = rj & 0xFFFF; rl = (rj >> 16) & 0x1FF; wj = 1.0f; }
            else      { nin = el[rj * 3]; rl = el[rj * 3 + 2];
                        wj = __shfl(wrec, slot); }
            float wsel = (slot < mm) ? wj : 0.0f;
            float4 a = loadF4(input, nin * 16 + k, bfI);
            float4 r = loadF4(relw, rl * 16 + k, bfR);
            float tx = a.x*r.x, ty = a.y*r.y, tz = a.z*r.z, tw = a.w*r.w;
            s4.x = fmaf(wsel, tx, s4.x); q4.x = fmaf(wsel*tx, tx, q4.x);
            s4.y = fmaf(wsel, ty, s4.y); q4.y = fmaf(wsel*ty, ty, q4.y);
            s4.z = fmaf(wsel, tz, s4.z); q4.z = fmaf(wsel*tz, tz, q4.z);
            s4.w = fmaf(wsel, tw, s4.w); q4.w = fmaf(wsel*tw, tw, q4.w);
          }
        }
      }
    } else {
      float degc = 0.f;
      for (int e0 = g; e0 < NE; e0 += 4) {
        int nout = el[e0 * 3 + 1];
        if (nout != n) continue;
        degc += 1.0f;
        int nin = el[e0 * 3], rl = el[e0 * 3 + 2];
        float wj = ones ? 1.0f : loadF(ew, e0, bfE);
        float4 a = loadF4(input, nin * 16 + k, bfI);
        float4 r = loadF4(relw, rl * 16 + k, bfR);
        float tx = wj*a.x*r.x, ty = wj*a.y*r.y, tz = wj*a.z*r.z,
              tw = wj*a.w*r.w;
        s4.x += tx; q4.x = fmaf(tx, tx, q4.x);
        s4.y += ty; q4.y = fmaf(ty, ty, q4.y);
        s4.z += tz; q4.z = fmaf(tz, tz, q4.z);
        s4.w += tw; q4.w = fmaf(tw, tw, q4.w);
      }
      degc += __shfl_xor(degc, 16); degc += __shfl_xor(degc, 32);
      degf = degc;
    }
    s4.x += __shfl_xor(s4.x, 16); s4.x += __shfl_xor(s4.x, 32);
    s4.y += __shfl_xor(s4.y, 16); s4.y += __shfl_xor(s4.y, 32);
    s4.z += __shfl_xor(s4.z, 16); s4.z += __shfl_xor(s4.z, 32);
    s4.w += __shfl_xor(s4.w, 16); s4.w += __shfl_xor(s4.w, 32);
    q4.x += __shfl_xor(q4.x, 16); q4.x += __shfl_xor(q4.x, 32);
    q4.y += __shfl_xor(q4.y, 16); q4.y += __shfl_xor(q4.y, 32);
    q4.z += __shfl_xor(q4.z, 16); q4.z += __shfl_xor(q4.z, 32);
    q4.w += __shfl_xor(q4.w, 16); q4.w += __shfl_xor(q4.w, 32);
    if (g == 0) {
      float4 b4 = loadF4(boundary, n * 16 + k, bfB);
      float dg = degf + 1.0f;
      float sv, qv;
      bf16x4 u;
      sv = (s4.x + b4.x) / dg; qv = (q4.x + b4.x * b4.x) / dg;
      u[0] = (__bf16)sqrtf(fmaxf(qv - sv * sv, 1e-6f));
      sv = (s4.y + b4.y) / dg; qv = (q4.y + b4.y * b4.y) / dg;
      u[1] = (__bf16)sqrtf(fmaxf(qv - sv * sv, 1e-6f));
      sv = (s4.z + b4.z) / dg; qv = (q4.z + b4.z * b4.z) / dg;
      u[2] = (__bf16)sqrtf(fmaxf(qv - sv * sv, 1e-6f));
      sv = (s4.w + b4.w) / dg; qv = (q4.w + b4.w * b4.w) / dg;
      u[3] = (__bf16)sqrtf(fmaxf(qv - sv * sv, 1e-6f));
      *(bf16x4*)&updb[row][4 * k] = u;
    }
  }
  __syncthreads();

  int tt = wv >> 1, chh = wv & 1;
  bf16x8 af0 = *(const bf16x8*)&updb[tt * 16 + (ln & 15)][q * 8];
  bf16x8 af1 = *(const bf16x8*)&updb[tt * 16 + (ln & 15)][32 + q * 8];
  #pragma unroll
  for (int hh = 0; hh < 2; ++hh) {
    int cc = chh * 32 + hh * 16 + (ln & 15);
    bf16x8 bfr0, bfr1;
    #pragma unroll
    for (int j = 0; j < 8; ++j) {
      bfr0[j] = (__bf16)loadF(W, cc * 64 + q * 8 + j, bfW);
      bfr1[j] = (__bf16)loadF(W, cc * 64 + 32 + q * 8 + j, bfW);
    }
    float bias = loadF(bv, cc, bfW);
    f32x4 accv = {0.f, 0.f, 0.f, 0.f};
    accv = __builtin_amdgcn_mfma_f32_16x16x32_bf16(af0, bfr0, accv, 0, 0, 0);
    accv = __builtin_amdgcn_mfma_f32_16x16x32_bf16(af1, bfr1, accv, 0, 0, 0);
    #pragma unroll
    for (int i = 0; i < 4; ++i) {
      int nn = n0 + tt * 16 + q * 4 + i;
      if (nn < hi) {
        float v = accv[i] + bias;
        if (bfI) ((__hip_bfloat16*)out)[nn * 64 + cc] = __float2bfloat16(v);
        else     ((float*)out)[nn * 64 + cc] = v;
      }
    }
  }
}

extern "C" void kernel_launch(void* const* d_in, const int* in_sizes, int n_in,
                              void* d_out, int out_size, void* d_ws, size_t ws_size,
                              hipStream_t stream) {
  const void* input    = d_in[0];
  const void* boundary = d_in[1];
  const int*  edges    = (const int*)d_in[2];
  const void* eweight  = d_in[3];
  const void* relw     = d_in[4];
  const void* W        = d_in[5];
  const void* bv       = d_in[6];

  int* wsI    = (int*)d_ws;
  int* flags  = wsI + OFF_FLAGS;
  int* bcurp  = wsI + OFF_BCURP;
  int* eidx   = wsI + OFF_EIDX;

  long avail = (long)(ws_size / 4) - OFF_EIDX;
  if (avail < 1) avail = 1;
  int padcap = 8192;
  long bfit = avail / padcap;
  if (bfit < 1) { padcap = (int)avail; bfit = 1; }
  if (bfit > NBK) bfit = NBK;
  int npass = (int)((NBK + bfit - 1) / bfit);

  k_detect<<<1, 64, 0, stream>>>(input, boundary, relw, W, eweight,
                                 flags, bcurp);
  k_ew<<<(NE + 8191) / 8192, 256, 0, stream>>>(eweight, flags);

  const int PA_NB = (NE + CHUNK - 1) / CHUNK;
  for (int p = 0; p < npass; ++p) {
    int gb0 = (int)((long)NBK * p / npass);
    int gb1 = (int)((long)NBK * (p + 1) / npass);
    int hi = (gb1 * 128 < NN) ? gb1 * 128 : NN;
    k_parta<<<PA_NB, 1024, 0, stream>>>(edges, bcurp, eidx, flags,
                                        gb0, gb1, padcap);
    k_node<<<(gb1 - gb0) * 4, 256, 0, stream>>>(
        input, boundary, edges, eweight, relw, W, bv, bcurp, eidx, flags,
        d_out, gb0, hi, padcap);
  }
}